// Round 9
// baseline (264.848 us; speedup 1.0000x reference)
//
#include <hip/hip_runtime.h>
#include <cmath>

#define B_SZ  1024
#define NORB  128
#define NUP   32
#define HID   4096
#define NCORR (NORB * NUP)   // 4096
#define K1    (4 * NORB)     // 512, one-hot GEMM K-dim

typedef short  bf16x8 __attribute__((ext_vector_type(8)));
typedef float  f32x4  __attribute__((ext_vector_type(4)));

__device__ __forceinline__ unsigned short f2bf_rne(float f) {
    unsigned int u = __float_as_uint(f);
    u += 0x7FFFu + ((u >> 16) & 1u);
    return (unsigned short)(u >> 16);
}

// ---------------------------------------------------------------------------
// k_splitW: W [rows][4096] f32 -> hi/lo bf16 in MFMA B-FRAGMENT ORDER:
//   flat = ((nt*ktTot + kt)*64 + lane)*8 + j
//   nt=n>>4, kt=k>>5, lane=((k>>3)&3)*16 + (n&15), j=k&7.
// ---------------------------------------------------------------------------
__global__ __launch_bounds__(256) void k_splitW(const float* __restrict__ W,
                                                unsigned short* __restrict__ Bph,
                                                unsigned short* __restrict__ Bpl,
                                                int ktTot) {
    __shared__ float tile[64][33];
    int n0 = blockIdx.x * 32, k0 = blockIdx.y * 64;
    int t = threadIdx.x;

    int rl = t >> 3, c4 = (t & 7) * 4;
#pragma unroll
    for (int i = 0; i < 2; ++i) {
        int kl = rl + 32 * i;
        float4 v = *(const float4*)(W + (size_t)(k0 + kl) * 4096 + n0 + c4);
        tile[kl][c4 + 0] = v.x; tile[kl][c4 + 1] = v.y;
        tile[kl][c4 + 2] = v.z; tile[kl][c4 + 3] = v.w;
    }
    __syncthreads();

    int nl = t & 31, kg = t >> 5;
    int nt = (n0 + nl) >> 4;
    int kt = (k0 >> 5) + (kg >> 2);
    int lane_o = (kg & 3) * 16 + (nl & 15);
    size_t o = (((size_t)nt * ktTot + kt) * 64 + lane_o) * 8;

    unsigned short hi8[8], lo8[8];
#pragma unroll
    for (int j = 0; j < 8; ++j) {
        float v = tile[kg * 8 + j][nl];
        unsigned short hi = f2bf_rne(v);
        float fhi = __uint_as_float((unsigned int)hi << 16);
        hi8[j] = hi;
        lo8[j] = f2bf_rne(v - fhi);
    }
    *(bf16x8*)(Bph + o) = *(bf16x8*)hi8;
    *(bf16x8*)(Bpl + o) = *(bf16x8*)lo8;
}

// ---------------------------------------------------------------------------
// k_hidden3: h = relu(one_hot(x) @ (W1hi + W1lo) + b1).
// LDS-PINNED B pipeline (the gemm6-proven pattern): B frags loaded to regs
// one kt-pair ahead, death pinned at post-barrier LDS write; MFMA reads B
// from LDS. Fixes k_hidden2's sunk-prefetch latency exposure (~110 us).
// A generated in-register from 2-bit packed x (exact bf16 one-hot).
// Output: A-FRAGMENT-PACKED split-bf16:
//   flat = ((mt*128 + kt)*64 + lane)*8 + j, kt over HID/32.
// ---------------------------------------------------------------------------
__global__ __launch_bounds__(256, 2) void k_hidden3(const int* __restrict__ x,
                                                    const unsigned short* __restrict__ Bph,
                                                    const unsigned short* __restrict__ Bpl,
                                                    const float* __restrict__ b1,
                                                    unsigned short* __restrict__ h_hi,
                                                    unsigned short* __restrict__ h_lo) {
    __shared__ unsigned int sxp[64][8];                 //  2 KB
    __shared__ unsigned short BF[2][4][4][512];         // 32 KB [subkt][wave][frag]
    __shared__ float Ht[64][132];                       // 33.8 KB

    int n0 = blockIdx.x * 128;
    int m0 = blockIdx.y * 64;
    int t = threadIdx.x;
    int w = t >> 6, lane = t & 63;
    int lm = lane & 15, kq = lane >> 4;
    int wn = w * 32;

    // pack x for this m-tile: 64 rows x 8 dwords (2 bits/orbital)
#pragma unroll
    for (int i = 0; i < 2; ++i) {
        int id = t + 256 * i;            // 0..511
        int row = id >> 3, d = id & 7;
        const int* src = x + (size_t)(m0 + row) * NORB + d * 16;
        unsigned int dw = 0;
#pragma unroll
        for (int b = 0; b < 16; ++b) dw |= ((unsigned int)(src[b] & 3)) << (2 * b);
        sxp[row][d] = dw;
    }

    // B stream bases (wave-private n-fragments nt0, nt0+1); kt stride 512
    int nt0 = (n0 + wn) >> 4;
    const unsigned short* bh0 = Bph + (size_t)nt0 * (16 * 512) + (size_t)lane * 8;
    const unsigned short* bh1 = Bph + (size_t)(nt0 + 1) * (16 * 512) + (size_t)lane * 8;
    const unsigned short* bl0 = Bpl + (size_t)nt0 * (16 * 512) + (size_t)lane * 8;
    const unsigned short* bl1 = Bpl + (size_t)(nt0 + 1) * (16 * 512) + (size_t)lane * 8;

    f32x4 acc[4][2] = {};

    // prologue: regs for pair 0 (kt = 0, 1)
    bf16x8 r0 = *(const bf16x8*)(bh0);
    bf16x8 r1 = *(const bf16x8*)(bh1);
    bf16x8 r2 = *(const bf16x8*)(bl0);
    bf16x8 r3 = *(const bf16x8*)(bl1);
    bf16x8 r4 = *(const bf16x8*)(bh0 + 512);
    bf16x8 r5 = *(const bf16x8*)(bh1 + 512);
    bf16x8 r6 = *(const bf16x8*)(bl0 + 512);
    bf16x8 r7 = *(const bf16x8*)(bl1 + 512);

    __syncthreads();   // sxp ready (also orders first LDS writes below)

    for (int p = 0; p < 8; ++p) {
        if (p) __syncthreads();            // prior pair's LDS reads complete

        // stage B regs (loaded one pair ago) -> LDS; death point pinned here
        *(bf16x8*)&BF[0][w][0][lane * 8] = r0;
        *(bf16x8*)&BF[0][w][1][lane * 8] = r1;
        *(bf16x8*)&BF[0][w][2][lane * 8] = r2;
        *(bf16x8*)&BF[0][w][3][lane * 8] = r3;
        *(bf16x8*)&BF[1][w][0][lane * 8] = r4;
        *(bf16x8*)&BF[1][w][1][lane * 8] = r5;
        *(bf16x8*)&BF[1][w][2][lane * 8] = r6;
        *(bf16x8*)&BF[1][w][3][lane * 8] = r7;
        __syncthreads();

        // prefetch next pair (a full pair of MFMAs of slack before use)
        int kn = (p + 1 < 8) ? p + 1 : 7;
        r0 = *(const bf16x8*)(bh0 + (2 * kn) * 512);
        r1 = *(const bf16x8*)(bh1 + (2 * kn) * 512);
        r2 = *(const bf16x8*)(bl0 + (2 * kn) * 512);
        r3 = *(const bf16x8*)(bl1 + (2 * kn) * 512);
        r4 = *(const bf16x8*)(bh0 + (2 * kn + 1) * 512);
        r5 = *(const bf16x8*)(bh1 + (2 * kn + 1) * 512);
        r6 = *(const bf16x8*)(bl0 + (2 * kn + 1) * 512);
        r7 = *(const bf16x8*)(bl1 + (2 * kn + 1) * 512);

#pragma unroll
        for (int s = 0; s < 2; ++s) {
            int kt = 2 * p + s;
            // A fragments: orbitals i0 = kt*8 + kq*2, i1 = i0+1 (same dword)
            int i0 = kt * 8 + kq * 2;
            int dwIdx = i0 >> 4;
            int sh = (i0 & 15) * 2;
            bf16x8 af[4];
#pragma unroll
            for (int fm = 0; fm < 4; ++fm) {
                unsigned int dw = sxp[fm * 16 + lm][dwIdx];
                unsigned int c01 = (dw >> sh) & 0xFu;
                union { bf16x8 v; unsigned long long u[2]; } a;
                a.u[0] = 0x3F80ULL << ((c01 & 3u) * 16);
                a.u[1] = 0x3F80ULL << ((c01 >> 2) * 16);
                af[fm] = a.v;
            }

            bf16x8 b0h = *(const bf16x8*)&BF[s][w][0][lane * 8];
            bf16x8 b1h = *(const bf16x8*)&BF[s][w][1][lane * 8];
            bf16x8 b0l = *(const bf16x8*)&BF[s][w][2][lane * 8];
            bf16x8 b1l = *(const bf16x8*)&BF[s][w][3][lane * 8];

#pragma unroll
            for (int fm = 0; fm < 4; ++fm) {
                acc[fm][0] = __builtin_amdgcn_mfma_f32_16x16x32_bf16(af[fm], b0h, acc[fm][0], 0, 0, 0);
                acc[fm][0] = __builtin_amdgcn_mfma_f32_16x16x32_bf16(af[fm], b0l, acc[fm][0], 0, 0, 0);
                acc[fm][1] = __builtin_amdgcn_mfma_f32_16x16x32_bf16(af[fm], b1h, acc[fm][1], 0, 0, 0);
                acc[fm][1] = __builtin_amdgcn_mfma_f32_16x16x32_bf16(af[fm], b1l, acc[fm][1], 0, 0, 0);
            }
        }
    }

    // epilogue: bias+relu into LDS (D-layout), read back in A-frag order
    __syncthreads();   // all BF reads done (separate array, but cheap safety)
#pragma unroll
    for (int fm = 0; fm < 4; ++fm)
#pragma unroll
        for (int fn = 0; fn < 2; ++fn) {
            int n = wn + fn * 16 + lm;
            float bv = b1[n0 + n];
#pragma unroll
            for (int r = 0; r < 4; ++r)
                Ht[fm * 16 + kq * 4 + r][n] = fmaxf(acc[fm][fn][r] + bv, 0.f);
        }
    __syncthreads();

    size_t mt0 = (size_t)(m0 >> 4), kt0 = (size_t)(n0 >> 5);
#pragma unroll
    for (int fi = 0; fi < 4; ++fi) {
        int f = w * 4 + fi;
        int mt = f >> 2, ktn = f & 3;
        int m = mt * 16 + lm;
        int kn = ktn * 32 + kq * 8;
        float4 v0 = *(const float4*)&Ht[m][kn];
        float4 v1 = *(const float4*)&Ht[m][kn + 4];
        float vv[8] = {v0.x, v0.y, v0.z, v0.w, v1.x, v1.y, v1.z, v1.w};
        unsigned short hi8[8], lo8[8];
#pragma unroll
        for (int j = 0; j < 8; ++j) {
            unsigned short hi = f2bf_rne(vv[j]);
            float fhi = __uint_as_float((unsigned int)hi << 16);
            hi8[j] = hi;
            lo8[j] = f2bf_rne(vv[j] - fhi);
        }
        size_t o = (((mt0 + mt) * 128 + (kt0 + ktn)) * 64 + lane) * 8;
        *(bf16x8*)(h_hi + o) = *(bf16x8*)hi8;
        *(bf16x8*)(h_lo + o) = *(bf16x8*)lo8;
    }
}

// ---------------------------------------------------------------------------
// f32 fallback hidden
// ---------------------------------------------------------------------------
__global__ __launch_bounds__(256) void k_hidden_f32(const int* __restrict__ x,
                                                    const float* __restrict__ W1,
                                                    const float* __restrict__ b1,
                                                    float* __restrict__ h) {
    int b = blockIdx.x, tid = threadIdx.x;
    __shared__ int sx[NORB];
    if (tid < NORB) sx[tid] = x[b * NORB + tid];
    __syncthreads();
    float acc[16];
#pragma unroll
    for (int u = 0; u < 16; ++u) acc[u] = b1[tid + 256 * u];
    for (int i = 0; i < NORB; ++i) {
        const float* row = W1 + (size_t)(4 * i + sx[i]) * HID;
#pragma unroll
        for (int u = 0; u < 16; ++u) acc[u] += row[tid + 256 * u];
    }
    float* hb = h + (size_t)b * HID;
#pragma unroll
    for (int u = 0; u < 16; ++u) hb[tid + 256 * u] = fmaxf(acc[u], 0.f);
}

// ---------------------------------------------------------------------------
// k_gemm6: corr = (h_hi+h_lo)@W2_hi + h_hi@W2_lo + b2 (unchanged, round 8).
// ---------------------------------------------------------------------------
__global__ __launch_bounds__(256, 2) void k_gemm6(const unsigned short* __restrict__ Ahp,
                                                  const unsigned short* __restrict__ Alp,
                                                  const unsigned short* __restrict__ Bph,
                                                  const unsigned short* __restrict__ Bpl,
                                                  const float* __restrict__ bias,
                                                  float* __restrict__ C) {
    __shared__ unsigned short AF[2][2][4][512];

    int n0 = blockIdx.x * 128;
    int m0 = blockIdx.y * 64;
    int t = threadIdx.x;
    int w = t >> 6, lane = t & 63;
    int lm = lane & 15, kq = lane >> 4;
    int wn = w * 32;

    int mt0 = m0 >> 4;
    int nt0 = (n0 + wn) >> 4;

    const unsigned short* agh = Ahp + (size_t)(mt0 + w) * 65536 + (size_t)lane * 8;
    const unsigned short* agl = Alp + (size_t)(mt0 + w) * 65536 + (size_t)lane * 8;
    const unsigned short* bh0 = Bph + (size_t)nt0 * 65536 + (size_t)lane * 8;
    const unsigned short* bh1 = Bph + (size_t)(nt0 + 1) * 65536 + (size_t)lane * 8;
    const unsigned short* bl0 = Bpl + (size_t)nt0 * 65536 + (size_t)lane * 8;
    const unsigned short* bl1 = Bpl + (size_t)(nt0 + 1) * 65536 + (size_t)lane * 8;

    f32x4 acc[4][2] = {};

    float4 rh0 = *(const float4*)(agh);
    float4 rh1 = *(const float4*)(agh + 512);
    float4 rl0 = *(const float4*)(agl);
    float4 rl1 = *(const float4*)(agl + 512);

    for (int ktp = 0; ktp < 64; ++ktp) {
        if (ktp) __syncthreads();

        int o0 = (2 * ktp) * 512, o1 = o0 + 512;
        bf16x8 B00h = *(const bf16x8*)(bh0 + o0);
        bf16x8 B01h = *(const bf16x8*)(bh1 + o0);
        bf16x8 B00l = *(const bf16x8*)(bl0 + o0);
        bf16x8 B01l = *(const bf16x8*)(bl1 + o0);
        bf16x8 B10h = *(const bf16x8*)(bh0 + o1);
        bf16x8 B11h = *(const bf16x8*)(bh1 + o1);
        bf16x8 B10l = *(const bf16x8*)(bl0 + o1);
        bf16x8 B11l = *(const bf16x8*)(bl1 + o1);

        *(float4*)&AF[0][0][w][lane * 8] = rh0;
        *(float4*)&AF[1][0][w][lane * 8] = rh1;
        *(float4*)&AF[0][1][w][lane * 8] = rl0;
        *(float4*)&AF[1][1][w][lane * 8] = rl1;
        __syncthreads();

        int kn = (ktp + 1 < 64) ? ktp + 1 : 63;
        rh0 = *(const float4*)(agh + (size_t)(2 * kn) * 512);
        rh1 = *(const float4*)(agh + (size_t)(2 * kn + 1) * 512);
        rl0 = *(const float4*)(agl + (size_t)(2 * kn) * 512);
        rl1 = *(const float4*)(agl + (size_t)(2 * kn + 1) * 512);

        bf16x8 ah[4], al[4];
#pragma unroll
        for (int fm = 0; fm < 4; ++fm) {
            ah[fm] = *(const bf16x8*)&AF[0][0][fm][lane * 8];
            al[fm] = *(const bf16x8*)&AF[0][1][fm][lane * 8];
        }
#pragma unroll
        for (int fm = 0; fm < 4; ++fm) {
            acc[fm][0] = __builtin_amdgcn_mfma_f32_16x16x32_bf16(ah[fm], B00h, acc[fm][0], 0, 0, 0);
            acc[fm][0] = __builtin_amdgcn_mfma_f32_16x16x32_bf16(al[fm], B00h, acc[fm][0], 0, 0, 0);
            acc[fm][0] = __builtin_amdgcn_mfma_f32_16x16x32_bf16(ah[fm], B00l, acc[fm][0], 0, 0, 0);
            acc[fm][1] = __builtin_amdgcn_mfma_f32_16x16x32_bf16(ah[fm], B01h, acc[fm][1], 0, 0, 0);
            acc[fm][1] = __builtin_amdgcn_mfma_f32_16x16x32_bf16(al[fm], B01h, acc[fm][1], 0, 0, 0);
            acc[fm][1] = __builtin_amdgcn_mfma_f32_16x16x32_bf16(ah[fm], B01l, acc[fm][1], 0, 0, 0);
        }

#pragma unroll
        for (int fm = 0; fm < 4; ++fm) {
            ah[fm] = *(const bf16x8*)&AF[1][0][fm][lane * 8];
            al[fm] = *(const bf16x8*)&AF[1][1][fm][lane * 8];
        }
#pragma unroll
        for (int fm = 0; fm < 4; ++fm) {
            acc[fm][0] = __builtin_amdgcn_mfma_f32_16x16x32_bf16(ah[fm], B10h, acc[fm][0], 0, 0, 0);
            acc[fm][0] = __builtin_amdgcn_mfma_f32_16x16x32_bf16(al[fm], B10h, acc[fm][0], 0, 0, 0);
            acc[fm][0] = __builtin_amdgcn_mfma_f32_16x16x32_bf16(ah[fm], B10l, acc[fm][0], 0, 0, 0);
            acc[fm][1] = __builtin_amdgcn_mfma_f32_16x16x32_bf16(ah[fm], B11h, acc[fm][1], 0, 0, 0);
            acc[fm][1] = __builtin_amdgcn_mfma_f32_16x16x32_bf16(al[fm], B11h, acc[fm][1], 0, 0, 0);
            acc[fm][1] = __builtin_amdgcn_mfma_f32_16x16x32_bf16(ah[fm], B11l, acc[fm][1], 0, 0, 0);
        }
    }

#pragma unroll
    for (int fm = 0; fm < 4; ++fm)
#pragma unroll
        for (int fn = 0; fn < 2; ++fn) {
            int n = n0 + wn + fn * 16 + lm;
            float bv = bias[n];
#pragma unroll
            for (int r = 0; r < 4; ++r) {
                int m = m0 + fm * 16 + kq * 4 + r;
                C[(size_t)m * NCORR + n] = acc[fm][fn][r] + bv;
            }
        }
}

// ---------------------------------------------------------------------------
// f32 fallback GEMM (round-2 kernel, unchanged)
// ---------------------------------------------------------------------------
#define BM 64
#define BN 64
#define BK 32
__global__ __launch_bounds__(256) void k_gemm(const float* __restrict__ A,
                                              const float* __restrict__ Bm,
                                              const float* __restrict__ bias,
                                              float* __restrict__ C) {
    __shared__ float As[BK][68];
    __shared__ float Bs[BK][BN];
    int n0 = blockIdx.x * BN, m0 = blockIdx.y * BM;
    int tid = threadIdx.x;
    int tm = tid >> 4, tn = tid & 15;
    int am = tid >> 3, ak = (tid & 7) * 4;
    int bk = tid >> 4, bn = (tid & 15) * 4;
    float acc[4][4] = {};
    for (int k0 = 0; k0 < HID; k0 += BK) {
#pragma unroll
        for (int s = 0; s < 2; ++s) {
            int m = am + 32 * s;
            float4 v = *(const float4*)(A + (size_t)(m0 + m) * HID + k0 + ak);
            As[ak + 0][m] = v.x; As[ak + 1][m] = v.y;
            As[ak + 2][m] = v.z; As[ak + 3][m] = v.w;
        }
#pragma unroll
        for (int s = 0; s < 2; ++s) {
            int k = bk + 16 * s;
            float4 v = *(const float4*)(Bm + (size_t)(k0 + k) * NCORR + n0 + bn);
            *(float4*)&Bs[k][bn] = v;
        }
        __syncthreads();
#pragma unroll
        for (int kk = 0; kk < BK; ++kk) {
            float4 a = *(const float4*)&As[kk][tm * 4];
            float4 bv = *(const float4*)&Bs[kk][tn * 4];
            float av[4] = {a.x, a.y, a.z, a.w};
            float bb[4] = {bv.x, bv.y, bv.z, bv.w};
#pragma unroll
            for (int i = 0; i < 4; ++i)
#pragma unroll
                for (int j = 0; j < 4; ++j) acc[i][j] += av[i] * bb[j];
        }
        __syncthreads();
    }
#pragma unroll
    for (int i = 0; i < 4; ++i) {
        int m = m0 + tm * 4 + i;
        float4 o;
        o.x = acc[i][0] + bias[n0 + tn * 4 + 0];
        o.y = acc[i][1] + bias[n0 + tn * 4 + 1];
        o.z = acc[i][2] + bias[n0 + tn * 4 + 2];
        o.w = acc[i][3] + bias[n0 + tn * 4 + 3];
        *(float4*)(C + (size_t)m * NCORR + n0 + tn * 4) = o;
    }
}

// ---------------------------------------------------------------------------
// Kernel C: gather + 32x32 LU (partial pivoting) per spin, planar complex out.
// ---------------------------------------------------------------------------
__global__ __launch_bounds__(128) void k_det(const int* __restrict__ x,
                                             const float* __restrict__ orbitals,
                                             const float* __restrict__ corr,
                                             float* __restrict__ out,
                                             int imag_off) {
    int b = blockIdx.x, tid = threadIdx.x;
    __shared__ int sx[NORB];
    __shared__ int yup[NUP], ydn[NUP];
    __shared__ float M[2][NUP][NUP + 1];
    __shared__ float rlog[2];
    __shared__ int rneg[2];

    sx[tid] = x[b * NORB + tid];
    __syncthreads();

    int occ = sx[tid];
    if (occ & 1) {
        int r = 0;
        for (int i = 0; i < tid; ++i) r += sx[i] & 1;
        yup[r] = tid;
    }
    if (occ & 2) {
        int r = 0;
        for (int i = 0; i < tid; ++i) r += (sx[i] >> 1) & 1;
        ydn[r] = tid;
    }
    __syncthreads();

    const float* cb = corr + (size_t)b * NCORR;
    for (int idx = tid; idx < 2 * NUP * NUP; idx += 128) {
        int s = idx >> 10;
        int i = (idx >> 5) & 31;
        int j = idx & 31;
        int r = s ? ydn[i] : yup[i];
        M[s][i][j] = orbitals[r * NUP + j] + cb[r * NUP + j];
    }
    __syncthreads();

    int wv = tid >> 6, lane = tid & 63;
    float (*Mm)[NUP + 1] = M[wv];
    float logdet = 0.f;
    int neg = 0;

    for (int k = 0; k < NUP; ++k) {
        float v = (lane >= k && lane < NUP) ? fabsf(Mm[lane][k]) : -1.f;
        int pi = lane;
#pragma unroll
        for (int off = 32; off > 0; off >>= 1) {
            float v2 = __shfl_down(v, off);
            int p2 = __shfl_down(pi, off);
            if (v2 > v) { v = v2; pi = p2; }
        }
        int p = __shfl(pi, 0);

        if (p != k) {
            if (lane < NUP) {
                float t1 = Mm[k][lane];
                Mm[k][lane] = Mm[p][lane];
                Mm[p][lane] = t1;
            }
            neg ^= 1;
        }
        __syncthreads();

        float pv = Mm[k][k];
        logdet += logf(fabsf(pv));
        if (pv < 0.f) neg ^= 1;

        int row = k + 1 + (lane & 31);
        int half = lane >> 5;
        if (row < NUP) {
            float f = Mm[row][k] / pv;
            for (int j = k + 1 + half; j < NUP; j += 2)
                Mm[row][j] -= f * Mm[k][j];
        }
        __syncthreads();
    }

    if (lane == 0) { rlog[wv] = logdet; rneg[wv] = neg; }
    __syncthreads();
    if (tid == 0) {
        out[b] = rlog[0] + rlog[1];
        if (imag_off > 0)
            out[imag_off + b] =
                (rneg[0] ^ rneg[1]) ? 3.14159265358979323846f : 0.f;
    }
}

// ---------------------------------------------------------------------------
extern "C" void kernel_launch(void* const* d_in, const int* in_sizes, int n_in,
                              void* d_out, int out_size, void* d_ws, size_t ws_size,
                              hipStream_t stream) {
    const int*   x        = (const int*)d_in[0];
    const float* orbitals = (const float*)d_in[1];
    const float* W1       = (const float*)d_in[2];
    const float* b1       = (const float*)d_in[3];
    const float* W2       = (const float*)d_in[4];
    const float* b2       = (const float*)d_in[5];
    float* out = (float*)d_out;
    int imag_off = (out_size == 2 * B_SZ) ? B_SZ : 0;

    const size_t need = (size_t)96 * 1024 * 1024;
    if (ws_size >= need) {
        unsigned short* h_hi = (unsigned short*)d_ws;                    //  8 MB (A-frag packed)
        unsigned short* h_lo = h_hi + (size_t)B_SZ * HID;                //  8 MB
        unsigned short* Bph  = h_lo + (size_t)B_SZ * HID;                // 32 MB (B-frag packed)
        unsigned short* Bpl  = Bph + (size_t)HID * NCORR;                // 32 MB
        float*          corr = (float*)(Bpl + (size_t)HID * NCORR);     // 16 MB

        // W1-pack lives INSIDE corr (consumed by k_hidden3 before k_gemm6
        // writes corr).
        unsigned short* W1ph = (unsigned short*)corr;                    // 4 MB
        unsigned short* W1pl = W1ph + (size_t)K1 * HID;                  // 4 MB

        k_splitW<<<dim3(HID / 32, K1 / 64), 256, 0, stream>>>(W1, W1ph, W1pl, 16);
        k_splitW<<<dim3(NCORR / 32, HID / 64), 256, 0, stream>>>(W2, Bph, Bpl, 128);

        k_hidden3<<<dim3(HID / 128, B_SZ / 64), 256, 0, stream>>>(x, W1ph, W1pl, b1, h_hi, h_lo);

        dim3 g2(NCORR / 128, B_SZ / 64);    // 32 x 16 = 512 blocks
        k_gemm6<<<g2, 256, 0, stream>>>(h_hi, h_lo, Bph, Bpl, b2, corr);
        k_det<<<B_SZ, 128, 0, stream>>>(x, orbitals, corr, out, imag_off);
    } else {
        float* h    = (float*)d_ws;
        float* corr = h + (size_t)B_SZ * HID;
        k_hidden_f32<<<B_SZ, 256, 0, stream>>>(x, W1, b1, h);
        dim3 g2(NCORR / BN, B_SZ / BM);
        k_gemm<<<g2, 256, 0, stream>>>(h, W2, b2, corr);
        k_det<<<B_SZ, 128, 0, stream>>>(x, orbitals, corr, out, imag_off);
    }
}

// Round 10
// 239.462 us; speedup vs baseline: 1.1060x; 1.1060x over previous
//
#include <hip/hip_runtime.h>
#include <cmath>

#define B_SZ  1024
#define NORB  128
#define NUP   32
#define HID   4096
#define NCORR (NORB * NUP)   // 4096
#define K1    (4 * NORB)     // 512, one-hot GEMM K-dim

typedef short    bf16x8 __attribute__((ext_vector_type(8)));
typedef _Float16 f16x8  __attribute__((ext_vector_type(8)));
typedef float    f32x4  __attribute__((ext_vector_type(4)));

__device__ __forceinline__ unsigned short f2bf_rne(float f) {
    unsigned int u = __float_as_uint(f);
    u += 0x7FFFu + ((u >> 16) & 1u);
    return (unsigned short)(u >> 16);
}

// ---------------------------------------------------------------------------
// k_splitW: W [rows][4096] f32 -> hi/lo bf16 in MFMA B-FRAGMENT ORDER
// (used for W1, ktTot=16). flat = ((nt*ktTot+kt)*64 + lane)*8 + j.
// ---------------------------------------------------------------------------
__global__ __launch_bounds__(256) void k_splitW(const float* __restrict__ W,
                                                unsigned short* __restrict__ Bph,
                                                unsigned short* __restrict__ Bpl,
                                                int ktTot) {
    __shared__ float tile[64][33];
    int n0 = blockIdx.x * 32, k0 = blockIdx.y * 64;
    int t = threadIdx.x;

    int rl = t >> 3, c4 = (t & 7) * 4;
#pragma unroll
    for (int i = 0; i < 2; ++i) {
        int kl = rl + 32 * i;
        float4 v = *(const float4*)(W + (size_t)(k0 + kl) * 4096 + n0 + c4);
        tile[kl][c4 + 0] = v.x; tile[kl][c4 + 1] = v.y;
        tile[kl][c4 + 2] = v.z; tile[kl][c4 + 3] = v.w;
    }
    __syncthreads();

    int nl = t & 31, kg = t >> 5;
    int nt = (n0 + nl) >> 4;
    int kt = (k0 >> 5) + (kg >> 2);
    int lane_o = (kg & 3) * 16 + (nl & 15);
    size_t o = (((size_t)nt * ktTot + kt) * 64 + lane_o) * 8;

    unsigned short hi8[8], lo8[8];
#pragma unroll
    for (int j = 0; j < 8; ++j) {
        float v = tile[kg * 8 + j][nl];
        unsigned short hi = f2bf_rne(v);
        float fhi = __uint_as_float((unsigned int)hi << 16);
        hi8[j] = hi;
        lo8[j] = f2bf_rne(v - fhi);
    }
    *(bf16x8*)(Bph + o) = *(bf16x8*)hi8;
    *(bf16x8*)(Bpl + o) = *(bf16x8*)lo8;
}

// ---------------------------------------------------------------------------
// k_splitW16: W2 f32 -> f16 hi + f16 (lo*2048) in B-FRAGMENT ORDER (ktTot=128).
// lo pre-scaled by 2048 so it stays in f16 normal range (W2_lo ~4e-5 would be
// subnormal; MFMA denorm behavior unverified). gemm7 epilogue multiplies the
// lo accumulator by 1/2048.
// ---------------------------------------------------------------------------
__global__ __launch_bounds__(256) void k_splitW16(const float* __restrict__ W,
                                                  _Float16* __restrict__ Bph,
                                                  _Float16* __restrict__ Bpl) {
    __shared__ float tile[64][33];
    int n0 = blockIdx.x * 32, k0 = blockIdx.y * 64;
    int t = threadIdx.x;

    int rl = t >> 3, c4 = (t & 7) * 4;
#pragma unroll
    for (int i = 0; i < 2; ++i) {
        int kl = rl + 32 * i;
        float4 v = *(const float4*)(W + (size_t)(k0 + kl) * 4096 + n0 + c4);
        tile[kl][c4 + 0] = v.x; tile[kl][c4 + 1] = v.y;
        tile[kl][c4 + 2] = v.z; tile[kl][c4 + 3] = v.w;
    }
    __syncthreads();

    int nl = t & 31, kg = t >> 5;
    int nt = (n0 + nl) >> 4;
    int kt = (k0 >> 5) + (kg >> 2);
    int lane_o = (kg & 3) * 16 + (nl & 15);
    size_t o = (((size_t)nt * 128 + kt) * 64 + lane_o) * 8;

    f16x8 hi8, lo8;
#pragma unroll
    for (int j = 0; j < 8; ++j) {
        float v = tile[kg * 8 + j][nl];
        _Float16 hi = (_Float16)v;
        hi8[j] = hi;
        lo8[j] = (_Float16)((v - (float)hi) * 2048.0f);
    }
    *(f16x8*)(Bph + o) = hi8;
    *(f16x8*)(Bpl + o) = lo8;
}

// ---------------------------------------------------------------------------
// k_hidden3: h = relu(one_hot(x) @ (W1hi + W1lo) + b1), f32 acc via bf16 MFMA
// (exact one-hot A generated from 2-bit packed x; W1 split bf16 -> h is
// f32-accurate). Output: SINGLE f16 stream, A-FRAGMENT-PACKED:
//   flat = ((mt*128 + kt)*64 + lane)*8 + j, kt over HID/32.
// ---------------------------------------------------------------------------
__global__ __launch_bounds__(256, 2) void k_hidden3(const int* __restrict__ x,
                                                    const unsigned short* __restrict__ Bph,
                                                    const unsigned short* __restrict__ Bpl,
                                                    const float* __restrict__ b1,
                                                    _Float16* __restrict__ h16) {
    __shared__ unsigned int sxp[64][8];                 //  2 KB
    __shared__ unsigned short BF[2][4][4][512];         // 32 KB
    __shared__ float Ht[64][132];                       // 33.8 KB

    int n0 = blockIdx.x * 128;
    int m0 = blockIdx.y * 64;
    int t = threadIdx.x;
    int w = t >> 6, lane = t & 63;
    int lm = lane & 15, kq = lane >> 4;
    int wn = w * 32;

    // pack x for this m-tile: 64 rows x 8 dwords (2 bits/orbital)
#pragma unroll
    for (int i = 0; i < 2; ++i) {
        int id = t + 256 * i;
        int row = id >> 3, d = id & 7;
        const int* src = x + (size_t)(m0 + row) * NORB + d * 16;
        unsigned int dw = 0;
#pragma unroll
        for (int b = 0; b < 16; ++b) dw |= ((unsigned int)(src[b] & 3)) << (2 * b);
        sxp[row][d] = dw;
    }

    int nt0 = (n0 + wn) >> 4;
    const unsigned short* bh0 = Bph + (size_t)nt0 * (16 * 512) + (size_t)lane * 8;
    const unsigned short* bh1 = Bph + (size_t)(nt0 + 1) * (16 * 512) + (size_t)lane * 8;
    const unsigned short* bl0 = Bpl + (size_t)nt0 * (16 * 512) + (size_t)lane * 8;
    const unsigned short* bl1 = Bpl + (size_t)(nt0 + 1) * (16 * 512) + (size_t)lane * 8;

    f32x4 acc[4][2] = {};

    bf16x8 r0 = *(const bf16x8*)(bh0);
    bf16x8 r1 = *(const bf16x8*)(bh1);
    bf16x8 r2 = *(const bf16x8*)(bl0);
    bf16x8 r3 = *(const bf16x8*)(bl1);
    bf16x8 r4 = *(const bf16x8*)(bh0 + 512);
    bf16x8 r5 = *(const bf16x8*)(bh1 + 512);
    bf16x8 r6 = *(const bf16x8*)(bl0 + 512);
    bf16x8 r7 = *(const bf16x8*)(bl1 + 512);

    __syncthreads();   // sxp ready

    for (int p = 0; p < 8; ++p) {
        if (p) __syncthreads();

        *(bf16x8*)&BF[0][w][0][lane * 8] = r0;
        *(bf16x8*)&BF[0][w][1][lane * 8] = r1;
        *(bf16x8*)&BF[0][w][2][lane * 8] = r2;
        *(bf16x8*)&BF[0][w][3][lane * 8] = r3;
        *(bf16x8*)&BF[1][w][0][lane * 8] = r4;
        *(bf16x8*)&BF[1][w][1][lane * 8] = r5;
        *(bf16x8*)&BF[1][w][2][lane * 8] = r6;
        *(bf16x8*)&BF[1][w][3][lane * 8] = r7;
        __syncthreads();

        int kn = (p + 1 < 8) ? p + 1 : 7;
        r0 = *(const bf16x8*)(bh0 + (2 * kn) * 512);
        r1 = *(const bf16x8*)(bh1 + (2 * kn) * 512);
        r2 = *(const bf16x8*)(bl0 + (2 * kn) * 512);
        r3 = *(const bf16x8*)(bl1 + (2 * kn) * 512);
        r4 = *(const bf16x8*)(bh0 + (2 * kn + 1) * 512);
        r5 = *(const bf16x8*)(bh1 + (2 * kn + 1) * 512);
        r6 = *(const bf16x8*)(bl0 + (2 * kn + 1) * 512);
        r7 = *(const bf16x8*)(bl1 + (2 * kn + 1) * 512);

#pragma unroll
        for (int s = 0; s < 2; ++s) {
            int kt = 2 * p + s;
            int i0 = kt * 8 + kq * 2;
            int dwIdx = i0 >> 4;
            int sh = (i0 & 15) * 2;
            bf16x8 af[4];
#pragma unroll
            for (int fm = 0; fm < 4; ++fm) {
                unsigned int dw = sxp[fm * 16 + lm][dwIdx];
                unsigned int c01 = (dw >> sh) & 0xFu;
                union { bf16x8 v; unsigned long long u[2]; } a;
                a.u[0] = 0x3F80ULL << ((c01 & 3u) * 16);
                a.u[1] = 0x3F80ULL << ((c01 >> 2) * 16);
                af[fm] = a.v;
            }

            bf16x8 b0h = *(const bf16x8*)&BF[s][w][0][lane * 8];
            bf16x8 b1h = *(const bf16x8*)&BF[s][w][1][lane * 8];
            bf16x8 b0l = *(const bf16x8*)&BF[s][w][2][lane * 8];
            bf16x8 b1l = *(const bf16x8*)&BF[s][w][3][lane * 8];

#pragma unroll
            for (int fm = 0; fm < 4; ++fm) {
                acc[fm][0] = __builtin_amdgcn_mfma_f32_16x16x32_bf16(af[fm], b0h, acc[fm][0], 0, 0, 0);
                acc[fm][0] = __builtin_amdgcn_mfma_f32_16x16x32_bf16(af[fm], b0l, acc[fm][0], 0, 0, 0);
                acc[fm][1] = __builtin_amdgcn_mfma_f32_16x16x32_bf16(af[fm], b1h, acc[fm][1], 0, 0, 0);
                acc[fm][1] = __builtin_amdgcn_mfma_f32_16x16x32_bf16(af[fm], b1l, acc[fm][1], 0, 0, 0);
            }
        }
    }

    // epilogue: bias+relu into LDS (D-layout), read back in A-frag order, f16
    __syncthreads();
#pragma unroll
    for (int fm = 0; fm < 4; ++fm)
#pragma unroll
        for (int fn = 0; fn < 2; ++fn) {
            int n = wn + fn * 16 + lm;
            float bv = b1[n0 + n];
#pragma unroll
            for (int r = 0; r < 4; ++r)
                Ht[fm * 16 + kq * 4 + r][n] = fmaxf(acc[fm][fn][r] + bv, 0.f);
        }
    __syncthreads();

    size_t mt0 = (size_t)(m0 >> 4), kt0 = (size_t)(n0 >> 5);
#pragma unroll
    for (int fi = 0; fi < 4; ++fi) {
        int f = w * 4 + fi;
        int mt = f >> 2, ktn = f & 3;
        int m = mt * 16 + lm;
        int kn = ktn * 32 + kq * 8;
        float4 v0 = *(const float4*)&Ht[m][kn];
        float4 v1 = *(const float4*)&Ht[m][kn + 4];
        float vv[8] = {v0.x, v0.y, v0.z, v0.w, v1.x, v1.y, v1.z, v1.w};
        f16x8 o16;
#pragma unroll
        for (int j = 0; j < 8; ++j) o16[j] = (_Float16)vv[j];
        size_t o = (((mt0 + mt) * 128 + (kt0 + ktn)) * 64 + lane) * 8;
        *(f16x8*)(h16 + o) = o16;
    }
}

// ---------------------------------------------------------------------------
// f32 fallback hidden
// ---------------------------------------------------------------------------
__global__ __launch_bounds__(256) void k_hidden_f32(const int* __restrict__ x,
                                                    const float* __restrict__ W1,
                                                    const float* __restrict__ b1,
                                                    float* __restrict__ h) {
    int b = blockIdx.x, tid = threadIdx.x;
    __shared__ int sx[NORB];
    if (tid < NORB) sx[tid] = x[b * NORB + tid];
    __syncthreads();
    float acc[16];
#pragma unroll
    for (int u = 0; u < 16; ++u) acc[u] = b1[tid + 256 * u];
    for (int i = 0; i < NORB; ++i) {
        const float* row = W1 + (size_t)(4 * i + sx[i]) * HID;
#pragma unroll
        for (int u = 0; u < 16; ++u) acc[u] += row[tid + 256 * u];
    }
    float* hb = h + (size_t)b * HID;
#pragma unroll
    for (int u = 0; u < 16; ++u) hb[tid + 256 * u] = fmaxf(acc[u], 0.f);
}

// ---------------------------------------------------------------------------
// k_gemm7: corr = h16 @ W2hi16 + (h16 @ W2lo16')/2048 + b2, f16 MFMA, f32 acc.
// 2-term all-f16 scheme: A single stream (ds_reads halved vs gemm6), separate
// lo accumulator (scaled W2_lo avoids f16 subnormal flush). gemm6 skeleton:
// A frag-packed global -> regs -> LDS (pinned pipeline), B global -> VGPR.
// ---------------------------------------------------------------------------
__global__ __launch_bounds__(256, 2) void k_gemm7(const _Float16* __restrict__ Ap,
                                                  const _Float16* __restrict__ Bph,
                                                  const _Float16* __restrict__ Bpl,
                                                  const float* __restrict__ bias,
                                                  float* __restrict__ C) {
    __shared__ _Float16 AF[2][4][512];   // [subkt][mt][lane*8]: 8 KB

    int n0 = blockIdx.x * 128;
    int m0 = blockIdx.y * 64;
    int t = threadIdx.x;
    int w = t >> 6, lane = t & 63;
    int lm = lane & 15, kq = lane >> 4;
    int wn = w * 32;

    int mt0 = m0 >> 4;
    int nt0 = (n0 + wn) >> 4;

    const _Float16* ag  = Ap  + (size_t)(mt0 + w) * 65536 + (size_t)lane * 8;
    const _Float16* bh0 = Bph + (size_t)nt0 * 65536 + (size_t)lane * 8;
    const _Float16* bh1 = Bph + (size_t)(nt0 + 1) * 65536 + (size_t)lane * 8;
    const _Float16* bl0 = Bpl + (size_t)nt0 * 65536 + (size_t)lane * 8;
    const _Float16* bl1 = Bpl + (size_t)(nt0 + 1) * 65536 + (size_t)lane * 8;

    f32x4 accH[4][2] = {}, accL[4][2] = {};

    // prologue: A regs for pair 0 (kt = 0, 1)
    f16x8 r0 = *(const f16x8*)(ag);
    f16x8 r1 = *(const f16x8*)(ag + 512);

    for (int ktp = 0; ktp < 64; ++ktp) {
        if (ktp) __syncthreads();

        int o0 = (2 * ktp) * 512, o1 = o0 + 512;
        f16x8 B0h0 = *(const f16x8*)(bh0 + o0);
        f16x8 B0h1 = *(const f16x8*)(bh1 + o0);
        f16x8 B0l0 = *(const f16x8*)(bl0 + o0);
        f16x8 B0l1 = *(const f16x8*)(bl1 + o0);
        f16x8 B1h0 = *(const f16x8*)(bh0 + o1);
        f16x8 B1h1 = *(const f16x8*)(bh1 + o1);
        f16x8 B1l0 = *(const f16x8*)(bl0 + o1);
        f16x8 B1l1 = *(const f16x8*)(bl1 + o1);

        *(f16x8*)&AF[0][w][lane * 8] = r0;
        *(f16x8*)&AF[1][w][lane * 8] = r1;
        __syncthreads();

        int kn = (ktp + 1 < 64) ? ktp + 1 : 63;
        r0 = *(const f16x8*)(ag + (size_t)(2 * kn) * 512);
        r1 = *(const f16x8*)(ag + (size_t)(2 * kn + 1) * 512);

        f16x8 a0[4], a1[4];
#pragma unroll
        for (int fm = 0; fm < 4; ++fm) {
            a0[fm] = *(const f16x8*)&AF[0][fm][lane * 8];
            a1[fm] = *(const f16x8*)&AF[1][fm][lane * 8];
        }

#pragma unroll
        for (int fm = 0; fm < 4; ++fm) {
            accH[fm][0] = __builtin_amdgcn_mfma_f32_16x16x32_f16(a0[fm], B0h0, accH[fm][0], 0, 0, 0);
            accL[fm][0] = __builtin_amdgcn_mfma_f32_16x16x32_f16(a0[fm], B0l0, accL[fm][0], 0, 0, 0);
            accH[fm][1] = __builtin_amdgcn_mfma_f32_16x16x32_f16(a0[fm], B0h1, accH[fm][1], 0, 0, 0);
            accL[fm][1] = __builtin_amdgcn_mfma_f32_16x16x32_f16(a0[fm], B0l1, accL[fm][1], 0, 0, 0);
        }
#pragma unroll
        for (int fm = 0; fm < 4; ++fm) {
            accH[fm][0] = __builtin_amdgcn_mfma_f32_16x16x32_f16(a1[fm], B1h0, accH[fm][0], 0, 0, 0);
            accL[fm][0] = __builtin_amdgcn_mfma_f32_16x16x32_f16(a1[fm], B1l0, accL[fm][0], 0, 0, 0);
            accH[fm][1] = __builtin_amdgcn_mfma_f32_16x16x32_f16(a1[fm], B1h1, accH[fm][1], 0, 0, 0);
            accL[fm][1] = __builtin_amdgcn_mfma_f32_16x16x32_f16(a1[fm], B1l1, accL[fm][1], 0, 0, 0);
        }
    }

    const float ls = 1.0f / 2048.0f;
#pragma unroll
    for (int fm = 0; fm < 4; ++fm)
#pragma unroll
        for (int fn = 0; fn < 2; ++fn) {
            int n = n0 + wn + fn * 16 + lm;
            float bv = bias[n];
#pragma unroll
            for (int r = 0; r < 4; ++r) {
                int m = m0 + fm * 16 + kq * 4 + r;
                C[(size_t)m * NCORR + n] = accH[fm][fn][r] + ls * accL[fm][fn][r] + bv;
            }
        }
}

// ---------------------------------------------------------------------------
// f32 fallback GEMM (round-2 kernel, unchanged)
// ---------------------------------------------------------------------------
#define BM 64
#define BN 64
#define BK 32
__global__ __launch_bounds__(256) void k_gemm(const float* __restrict__ A,
                                              const float* __restrict__ Bm,
                                              const float* __restrict__ bias,
                                              float* __restrict__ C) {
    __shared__ float As[BK][68];
    __shared__ float Bs[BK][BN];
    int n0 = blockIdx.x * BN, m0 = blockIdx.y * BM;
    int tid = threadIdx.x;
    int tm = tid >> 4, tn = tid & 15;
    int am = tid >> 3, ak = (tid & 7) * 4;
    int bk = tid >> 4, bn = (tid & 15) * 4;
    float acc[4][4] = {};
    for (int k0 = 0; k0 < HID; k0 += BK) {
#pragma unroll
        for (int s = 0; s < 2; ++s) {
            int m = am + 32 * s;
            float4 v = *(const float4*)(A + (size_t)(m0 + m) * HID + k0 + ak);
            As[ak + 0][m] = v.x; As[ak + 1][m] = v.y;
            As[ak + 2][m] = v.z; As[ak + 3][m] = v.w;
        }
#pragma unroll
        for (int s = 0; s < 2; ++s) {
            int k = bk + 16 * s;
            float4 v = *(const float4*)(Bm + (size_t)(k0 + k) * NCORR + n0 + bn);
            *(float4*)&Bs[k][bn] = v;
        }
        __syncthreads();
#pragma unroll
        for (int kk = 0; kk < BK; ++kk) {
            float4 a = *(const float4*)&As[kk][tm * 4];
            float4 bv = *(const float4*)&Bs[kk][tn * 4];
            float av[4] = {a.x, a.y, a.z, a.w};
            float bb[4] = {bv.x, bv.y, bv.z, bv.w};
#pragma unroll
            for (int i = 0; i < 4; ++i)
#pragma unroll
                for (int j = 0; j < 4; ++j) acc[i][j] += av[i] * bb[j];
        }
        __syncthreads();
    }
#pragma unroll
    for (int i = 0; i < 4; ++i) {
        int m = m0 + tm * 4 + i;
        float4 o;
        o.x = acc[i][0] + bias[n0 + tn * 4 + 0];
        o.y = acc[i][1] + bias[n0 + tn * 4 + 1];
        o.z = acc[i][2] + bias[n0 + tn * 4 + 2];
        o.w = acc[i][3] + bias[n0 + tn * 4 + 3];
        *(float4*)(C + (size_t)m * NCORR + n0 + tn * 4) = o;
    }
}

// ---------------------------------------------------------------------------
// Kernel C: gather + 32x32 LU (partial pivoting) per spin, planar complex out.
// ---------------------------------------------------------------------------
__global__ __launch_bounds__(128) void k_det(const int* __restrict__ x,
                                             const float* __restrict__ orbitals,
                                             const float* __restrict__ corr,
                                             float* __restrict__ out,
                                             int imag_off) {
    int b = blockIdx.x, tid = threadIdx.x;
    __shared__ int sx[NORB];
    __shared__ int yup[NUP], ydn[NUP];
    __shared__ float M[2][NUP][NUP + 1];
    __shared__ float rlog[2];
    __shared__ int rneg[2];

    sx[tid] = x[b * NORB + tid];
    __syncthreads();

    int occ = sx[tid];
    if (occ & 1) {
        int r = 0;
        for (int i = 0; i < tid; ++i) r += sx[i] & 1;
        yup[r] = tid;
    }
    if (occ & 2) {
        int r = 0;
        for (int i = 0; i < tid; ++i) r += (sx[i] >> 1) & 1;
        ydn[r] = tid;
    }
    __syncthreads();

    const float* cb = corr + (size_t)b * NCORR;
    for (int idx = tid; idx < 2 * NUP * NUP; idx += 128) {
        int s = idx >> 10;
        int i = (idx >> 5) & 31;
        int j = idx & 31;
        int r = s ? ydn[i] : yup[i];
        M[s][i][j] = orbitals[r * NUP + j] + cb[r * NUP + j];
    }
    __syncthreads();

    int wv = tid >> 6, lane = tid & 63;
    float (*Mm)[NUP + 1] = M[wv];
    float logdet = 0.f;
    int neg = 0;

    for (int k = 0; k < NUP; ++k) {
        float v = (lane >= k && lane < NUP) ? fabsf(Mm[lane][k]) : -1.f;
        int pi = lane;
#pragma unroll
        for (int off = 32; off > 0; off >>= 1) {
            float v2 = __shfl_down(v, off);
            int p2 = __shfl_down(pi, off);
            if (v2 > v) { v = v2; pi = p2; }
        }
        int p = __shfl(pi, 0);

        if (p != k) {
            if (lane < NUP) {
                float t1 = Mm[k][lane];
                Mm[k][lane] = Mm[p][lane];
                Mm[p][lane] = t1;
            }
            neg ^= 1;
        }
        __syncthreads();

        float pv = Mm[k][k];
        logdet += logf(fabsf(pv));
        if (pv < 0.f) neg ^= 1;

        int row = k + 1 + (lane & 31);
        int half = lane >> 5;
        if (row < NUP) {
            float f = Mm[row][k] / pv;
            for (int j = k + 1 + half; j < NUP; j += 2)
                Mm[row][j] -= f * Mm[k][j];
        }
        __syncthreads();
    }

    if (lane == 0) { rlog[wv] = logdet; rneg[wv] = neg; }
    __syncthreads();
    if (tid == 0) {
        out[b] = rlog[0] + rlog[1];
        if (imag_off > 0)
            out[imag_off + b] =
                (rneg[0] ^ rneg[1]) ? 3.14159265358979323846f : 0.f;
    }
}

// ---------------------------------------------------------------------------
extern "C" void kernel_launch(void* const* d_in, const int* in_sizes, int n_in,
                              void* d_out, int out_size, void* d_ws, size_t ws_size,
                              hipStream_t stream) {
    const int*   x        = (const int*)d_in[0];
    const float* orbitals = (const float*)d_in[1];
    const float* W1       = (const float*)d_in[2];
    const float* b1       = (const float*)d_in[3];
    const float* W2       = (const float*)d_in[4];
    const float* b2       = (const float*)d_in[5];
    float* out = (float*)d_out;
    int imag_off = (out_size == 2 * B_SZ) ? B_SZ : 0;

    const size_t need = (size_t)96 * 1024 * 1024;
    if (ws_size >= need) {
        _Float16* h16  = (_Float16*)d_ws;                                //  8 MB (A-frag packed f16)
        _Float16* Bh16 = h16 + (size_t)B_SZ * HID;                       // 32 MB (W2 hi f16, B-frag)
        _Float16* Bl16 = Bh16 + (size_t)HID * NCORR;                     // 32 MB (W2 lo*2048 f16)
        float*    corr = (float*)(Bl16 + (size_t)HID * NCORR);           // 16 MB

        // W1-pack (bf16, for hidden3) lives INSIDE corr — consumed by
        // k_hidden3 before k_gemm7 writes corr.
        unsigned short* W1ph = (unsigned short*)corr;                    // 4 MB
        unsigned short* W1pl = W1ph + (size_t)K1 * HID;                  // 4 MB

        k_splitW<<<dim3(HID / 32, K1 / 64), 256, 0, stream>>>(W1, W1ph, W1pl, 16);
        k_splitW16<<<dim3(NCORR / 32, HID / 64), 256, 0, stream>>>(W2, Bh16, Bl16);

        k_hidden3<<<dim3(HID / 128, B_SZ / 64), 256, 0, stream>>>(x, W1ph, W1pl, b1, h16);

        dim3 g2(NCORR / 128, B_SZ / 64);    // 32 x 16 = 512 blocks
        k_gemm7<<<g2, 256, 0, stream>>>(h16, Bh16, Bl16, b2, corr);
        k_det<<<B_SZ, 128, 0, stream>>>(x, orbitals, corr, out, imag_off);
    } else {
        float* h    = (float*)d_ws;
        float* corr = h + (size_t)B_SZ * HID;
        k_hidden_f32<<<B_SZ, 256, 0, stream>>>(x, W1, b1, h);
        dim3 g2(NCORR / BN, B_SZ / BM);
        k_gemm<<<g2, 256, 0, stream>>>(h, W2, b2, corr);
        k_det<<<B_SZ, 128, 0, stream>>>(x, orbitals, corr, out, imag_off);
    }
}